// Round 3
// baseline (20410.020 us; speedup 1.0000x reference)
//
#include <hip/hip_runtime.h>
#include <cstdint>
#include <cstddef>

#define Bz 64
#define Tz 512
#define Iz 512
#define Hz 512
#define Cz 4096
#define NWG 256

typedef __attribute__((ext_vector_type(8))) short short8;
typedef __attribute__((ext_vector_type(4))) float floatx4;
typedef __attribute__((ext_vector_type(2))) float floatx2;
typedef unsigned long long u64;
typedef unsigned int u32;

union U16S8 { u64 u[2]; short8 s; };
union U8F2  { u64 u; float f[2]; };

__device__ __forceinline__ unsigned short f2bf(float f) {
  union { float f; unsigned u; } v; v.f = f;
  unsigned r = v.u + 0x7fffu + ((v.u >> 16) & 1u);
  return (unsigned short)(r >> 16);
}
__device__ __forceinline__ float bf2f(unsigned short h) {
  union { unsigned u; float f; } v; v.u = ((unsigned)h) << 16; return v.f;
}
__device__ __forceinline__ float sigmoidf_(float x) { return 1.0f / (1.0f + __expf(-x)); }

// 16-byte coherent read via two relaxed agent-scope u64 atomic loads (sc1: bypasses
// the non-coherent per-XCD L2 -> no acquire/invalidate needed anywhere).
__device__ __forceinline__ short8 ald16(const void* p) {
  u64* q = (u64*)p;
  U16S8 t;
  t.u[0] = __hip_atomic_load(q,     __ATOMIC_RELAXED, __HIP_MEMORY_SCOPE_AGENT);
  t.u[1] = __hip_atomic_load(q + 1, __ATOMIC_RELAXED, __HIP_MEMORY_SCOPE_AGENT);
  return t.s;
}

// ---------------- precast kernels (packed path) ----------------

__global__ __launch_bounds__(256) void precast_wpk(const float* __restrict__ Wi,
                                                   const float* __restrict__ Wst,
                                                   short* __restrict__ wpk) {
  int id = blockIdx.x * 256 + threadIdx.x;       // 0..2097151
  int l  = id & 63;
  int kt = (id >> 6) & 31;
  int nt = (id >> 11) & 3;
  int w  = id >> 13;
  int r  = nt * Cz + w * 16 + (l & 15);
  int k  = kt * 32 + (l >> 4) * 8;
  const float* p = (k < Iz) ? (Wi + (size_t)r * Iz + k)
                            : (Wst + (size_t)r * Hz + (k - Iz));
  short8 v;
  #pragma unroll
  for (int i = 0; i < 8; ++i) v[i] = (short)f2bf(p[i]);
  *(short8*)(wpk + (size_t)id * 8) = v;
}

__global__ __launch_bounds__(256) void precast_wpp(const float* __restrict__ Wp,
                                                   short* __restrict__ wpp) {
  int id = blockIdx.x * 256 + threadIdx.x;       // 0..262143
  int l  = id & 63;
  int kt = (id >> 6) & 15;
  int jc = (id >> 10) & 31;
  int kc = id >> 15;
  int j  = jc * 16 + (l & 15);
  int c  = kc * 512 + kt * 32 + (l >> 4) * 8;
  const float* p = Wp + (size_t)j * Cz + c;
  short8 v;
  #pragma unroll
  for (int i = 0; i < 8; ++i) v[i] = (short)f2bf(p[i]);
  *(short8*)(wpp + (size_t)id * 8) = v;
}

__global__ __launch_bounds__(256) void precast_x(const float* __restrict__ x,
                                                 unsigned short* __restrict__ xb) {
  size_t id = ((size_t)blockIdx.x * 256 + threadIdx.x) * 4;
  float4 v = *(const float4*)(x + id);
  ushort4 o;
  o.x = f2bf(v.x); o.y = f2bf(v.y); o.z = f2bf(v.z); o.w = f2bf(v.w);
  *(ushort4*)(xb + id) = o;
}

// ---------------- persistent kernel: 256 WGs x 512 thr ----------------
// WG w: gates for cells [w*16, w*16+16); proj tile kc=w>>5, jc=w&31.
// Coherence: h/abuf/accum/flags via relaxed sc1 atomics; read-only data cached.
// R2 restructure: 128 KB resident LDS tile [64 rows][8 chunks][16 grp^row] replaces
// the 2x16 KB double buffer. Each 512-k half staged in ONE shot (1 barrier), h-half
// loads issued to registers and hidden under the x-half MFMAs (T14 split). Barrier
// count per step: ~20 -> ~9. Inter-WG flag/sync structure byte-identical to the
// passing R1 kernel. Length skipping (lengths sorted decreasing) retained.
template <bool PK>
__global__ __launch_bounds__(512, 2)
void lstm_persist(const float* __restrict__ xf, const unsigned short* __restrict__ xb,
                  const float* __restrict__ Wi, const float* __restrict__ Wst,
                  const float* __restrict__ Wp,
                  const short* __restrict__ wpk, const short* __restrict__ wpp,
                  const float* __restrict__ bstate, const int* __restrict__ lens,
                  unsigned short* __restrict__ Hbuf,   // 2 x [64][512] bf16
                  float* __restrict__ accum,           // [64][512] fp32, zeroed
                  int* __restrict__ done,              // [32], monotonic
                  int* __restrict__ aflag,             // [256] stride 16 ints
                  int* __restrict__ hflag,             // [32]  stride 16 ints
                  unsigned short* __restrict__ abuf,   // 2 x [64][4096] bf16
                  float* __restrict__ outp, float* __restrict__ final_h,
                  float* __restrict__ final_c) {
  // [row 0..63][chunk 0..7][physgrp 0..15][8 shorts] ; phys = grp ^ (row & 15)
  __shared__ __align__(16) short kstage[64 * 8 * 16 * 8];   // 128 KB
  __shared__ float glds[64 * 64];                           // 16 KB, XOR-swizzled cols
  __shared__ int amLast;

  const int tid  = threadIdx.x;
  const int w    = blockIdx.x;
  const int lane = tid & 63;
  const int wv   = tid >> 6;        // 0..7
  const int lrow = lane & 15;
  const int lq   = lane >> 4;
  const int bt   = wv >> 1;         // gates batch 16-tile
  const int ntb  = (wv & 1) * 2;    // gates gate-pair base {0,2}
  const int jc   = w & 31;
  const int kc   = w >> 5;

  // block-head lengths (sorted decreasing => block max); uniform scalar loads
  const int l16_0 = lens[0];
  const int l16_1 = lens[16];
  const int l16_2 = lens[32];
  const int l16_3 = lens[48];

  // epilogue ownership: thread -> (batch b_e, cells cc2, cc2+1)
  const int b_e  = tid >> 3;        // 0..63
  const int cc2  = (tid & 7) * 2;   // 0..14
  const int cell2 = w * 16 + cc2;
  float bsv[4][2];
  #pragma unroll
  for (int g = 0; g < 4; ++g) {
    bsv[g][0] = bstate[g * Cz + cell2];
    bsv[g][1] = bstate[g * Cz + cell2 + 1];
  }
  const int len_e = lens[b_e];
  float c_reg[2] = {0.f, 0.f};

  // finalizer ownership: thread -> (batch b_f, cols j2, j2+1)
  const int b_f = tid >> 3;
  const int j2  = (tid & 7) * 2;
  const int jf  = jc * 16 + j2;
  const int len_f = lens[b_f];

  // staging geometry: iteration u covers row = u*8 + wv; lanes = 64 groups of 8 k
  const int sq   = lane >> 4;       // chunk-in-half 0..3
  const int sgrp = lane & 15;

  for (int t = 0; t < Tz; ++t) {
    const unsigned short* Hread = Hbuf + (size_t)(t & 1) * Bz * Hz;
    unsigned short* abufT = abuf + (size_t)(t & 1) * Bz * Cz;

    // active 16-row blocks this step (monotone non-increasing in t)
    const int nb16   = (t < l16_0) + (t < l16_1) + (t < l16_2) + (t < l16_3);
    const int nbrows = nb16 << 4;

    // =================== gates phase ===================
    floatx4 acc0 = {0.f, 0.f, 0.f, 0.f};
    floatx4 acc1 = {0.f, 0.f, 0.f, 0.f};

    // ---- stage x half (chunks 0..3) in one shot; overlaps the hflag poll ----
    #pragma unroll
    for (int u = 0; u < 8; ++u) {
      int row = u * 8 + wv;
      if (row >= nbrows) continue;             // wave-uniform skip
      short8 val;
      if (PK) {
        val = *(const short8*)(xb + ((size_t)row * Tz + t) * Iz + lane * 8);
      } else {
        const float* p = xf + ((size_t)row * Tz + t) * Iz + lane * 8;
        #pragma unroll
        for (int i = 0; i < 8; ++i) val[i] = (short)f2bf(p[i]);
      }
      int phys = sgrp ^ (row & 15);
      *(short8*)(&kstage[((row * 8 + sq) * 16 + phys) * 8]) = val;
    }

    // ---- wait h(t-1) ready ----
    if (tid < 32) {
      while (__hip_atomic_load(&hflag[tid * 16], __ATOMIC_RELAXED,
                               __HIP_MEMORY_SCOPE_AGENT) < t)
        __builtin_amdgcn_s_sleep(1);
    }
    __syncthreads();                           // x staged + h ready
    __asm__ volatile("" ::: "memory");

    // ---- issue h loads to registers (latency hides under x-half MFMAs) ----
    short8 hreg[8];
    #pragma unroll
    for (int u = 0; u < 8; ++u) {
      int row = u * 8 + wv;
      if (row < nbrows) hreg[u] = ald16(Hread + row * Hz + lane * 8);
    }

    auto gmfma = [&](int kt) {
      int g64  = kt * 4 + lq;
      int q    = g64 >> 4;
      int grp  = g64 & 15;
      int phys = grp ^ lrow;
      short8 afr = *(const short8*)(&kstage[(((bt * 16 + lrow) * 8 + q) * 16 + phys) * 8]);
      short8 bfr0, bfr1;
      if (PK) {
        const short* bp = wpk + ((((size_t)w * 4 + ntb) * 32 + kt) * 64 + lane) * 8;
        bfr0 = *(const short8*)bp;
        bfr1 = *(const short8*)(bp + (size_t)32 * 64 * 8);
      } else {
        #pragma unroll
        for (int hh = 0; hh < 2; ++hh) {
          int nt = ntb + hh;
          int r  = nt * Cz + w * 16 + lrow;
          int k  = kt * 32 + lq * 8;
          const float* p = (k < Iz) ? (Wi + (size_t)r * Iz + k)
                                    : (Wst + (size_t)r * Hz + (k - Iz));
          short8 v;
          #pragma unroll
          for (int i = 0; i < 8; ++i) v[i] = (short)f2bf(p[i]);
          if (hh == 0) bfr0 = v; else bfr1 = v;
        }
      }
      acc0 = __builtin_amdgcn_mfma_f32_16x16x32_bf16(afr, bfr0, acc0, 0, 0, 0);
      acc1 = __builtin_amdgcn_mfma_f32_16x16x32_bf16(afr, bfr1, acc1, 0, 0, 0);
    };

    // ---- x-half GEMM (chunks 0..3) while h loads are in flight ----
    if (bt < nb16) {
      #pragma unroll
      for (int kt = 0; kt < 16; ++kt) gmfma(kt);
    }

    // ---- write h to LDS (chunks 4..7) ----
    #pragma unroll
    for (int u = 0; u < 8; ++u) {
      int row = u * 8 + wv;
      if (row >= nbrows) continue;
      int phys = sgrp ^ (row & 15);
      *(short8*)(&kstage[((row * 8 + 4 + sq) * 16 + phys) * 8]) = hreg[u];
    }
    __syncthreads();                           // h staged

    // ---- h-half GEMM (chunks 4..7) ----
    if (bt < nb16) {
      #pragma unroll
      for (int kt = 16; kt < 32; ++kt) gmfma(kt);
    }

    if (bt < nb16) {  // spill gate tile to LDS; col n = gate*16 + cell, phys col = n ^ row
      const int sb0 = bt * 16 + lq * 4;
      const int n0  = ntb * 16 + lrow;
      #pragma unroll
      for (int r = 0; r < 4; ++r) {
        int row = sb0 + r;
        glds[row * 64 + ((n0 ^ row) & 63)]        = acc0[r];
        glds[row * 64 + (((n0 + 16) ^ row) & 63)] = acc1[r];
      }
    }
    __syncthreads();
    {  // fp32 epilogue: 2 cells per thread, c in registers, packed sc1 store
      if (b_e < nbrows) {
        float a_out[2];
        #pragma unroll
        for (int e = 0; e < 2; ++e) {
          int cc = cc2 + e;
          float g0 = glds[b_e * 64 + (((0  + cc) ^ b_e) & 63)] + bsv[0][e];
          float g1 = glds[b_e * 64 + (((16 + cc) ^ b_e) & 63)] + bsv[1][e];
          float g2 = glds[b_e * 64 + (((32 + cc) ^ b_e) & 63)] + bsv[2][e];
          float g3 = glds[b_e * 64 + (((48 + cc) ^ b_e) & 63)] + bsv[3][e];
          float mem = sigmoidf_(g0) * tanhf(g2) + sigmoidf_(g1) * c_reg[e];
          mem = fminf(fmaxf(mem, -3.f), 3.f);
          bool active = t < len_e;
          c_reg[e] = active ? mem : c_reg[e];
          a_out[e] = sigmoidf_(g3) * tanhf(mem);
        }
        u32 pk2 = (u32)f2bf(a_out[0]) | ((u32)f2bf(a_out[1]) << 16);
        __hip_atomic_store((u32*)abufT + (((size_t)b_e * Cz + cell2) >> 1), pk2,
                           __ATOMIC_RELAXED, __HIP_MEMORY_SCOPE_AGENT);
      }
      if (t == Tz - 1) {
        __builtin_nontemporal_store(c_reg[0], final_c + (size_t)b_e * Cz + cell2);
        __builtin_nontemporal_store(c_reg[1], final_c + (size_t)b_e * Cz + cell2 + 1);
      }
    }
    __syncthreads();            // drain all waves' abuf stores
    if (tid == 0)               // publish (release: waitcnt + wbl2, no invalidate)
      __hip_atomic_store(&aflag[w * 16], t + 1, __ATOMIC_RELEASE, __HIP_MEMORY_SCOPE_AGENT);

    // ---- wait: the 32 producers of abuf columns [kc*512, kc*512+512) ----
    if (tid < 32) {
      while (__hip_atomic_load(&aflag[(kc * 32 + tid) * 16], __ATOMIC_RELAXED,
                               __HIP_MEMORY_SCOPE_AGENT) < t + 1)
        __builtin_amdgcn_s_sleep(1);
    }
    __syncthreads();
    __asm__ volatile("" ::: "memory");

    // =================== projection phase ===================
    // stage abuf slice [64 rows][512 k] in one shot into chunks 0..3
    #pragma unroll
    for (int u = 0; u < 8; ++u) {
      int row = u * 8 + wv;
      if (row >= nbrows) continue;
      short8 v = ald16(abufT + (size_t)row * Cz + kc * 512 + lane * 8);
      int phys = sgrp ^ (row & 15);
      *(short8*)(&kstage[((row * 8 + sq) * 16 + phys) * 8]) = v;
    }
    __syncthreads();                           // proj inputs staged

    floatx4 pacc = {0.f, 0.f, 0.f, 0.f};
    if (wv < nb16) {  // live row-tiles only
      #pragma unroll
      for (int kt = 0; kt < 16; ++kt) {
        int g64  = kt * 4 + lq;
        int q    = g64 >> 4;
        int grp  = g64 & 15;
        int phys = grp ^ lrow;
        short8 afr = *(const short8*)(&kstage[(((wv * 16 + lrow) * 8 + q) * 16 + phys) * 8]);
        short8 bfr;
        if (PK) {
          bfr = *(const short8*)(wpp + ((((size_t)kc * 32 + jc) * 16 + kt) * 64 + lane) * 8);
        } else {
          int j = jc * 16 + lrow;
          int c = kc * 512 + kt * 32 + lq * 8;
          const float* p = Wp + (size_t)j * Cz + c;
          #pragma unroll
          for (int i = 0; i < 8; ++i) bfr[i] = (short)f2bf(p[i]);
        }
        pacc = __builtin_amdgcn_mfma_f32_16x16x32_bf16(afr, bfr, pacc, 0, 0, 0);
      }
      const int jcol = jc * 16 + lrow;
      #pragma unroll
      for (int r = 0; r < 4; ++r)
        unsafeAtomicAdd(&accum[(wv * 16 + lq * 4 + r) * Hz + jcol], pacc[r]);
    }
    __syncthreads();            // drain atomic adds
    if (tid == 0) {
      int old = __hip_atomic_fetch_add(&done[jc], 1, __ATOMIC_RELEASE, __HIP_MEMORY_SCOPE_AGENT);
      amLast = (old == 8 * (t + 1) - 1) ? 1 : 0;
    }
    __syncthreads();
    if (amLast) {  // last of 8 kc-partials: finalize h + output, 2 cols/thread
      unsigned short* Hwr = Hbuf + (size_t)((t & 1) ^ 1) * Bz * Hz;
      U8F2 pa;
      pa.u = __hip_atomic_load((u64*)(accum + b_f * Hz + jf),
                               __ATOMIC_RELAXED, __HIP_MEMORY_SCOPE_AGENT);
      float v0 = fminf(fmaxf(pa.f[0], -3.f), 3.f);
      float v1 = fminf(fmaxf(pa.f[1], -3.f), 3.f);
      bool active = t < len_f;
      u32 ho = __hip_atomic_load((u32*)Hread + ((b_f * Hz + jf) >> 1),
                                 __ATOMIC_RELAXED, __HIP_MEMORY_SCOPE_AGENT);
      float hn0 = active ? v0 : bf2f((unsigned short)(ho & 0xffff));
      float hn1 = active ? v1 : bf2f((unsigned short)(ho >> 16));
      floatx2 ov = {active ? v0 : 0.f, active ? v1 : 0.f};
      __builtin_nontemporal_store(ov, (floatx2*)(outp + ((size_t)b_f * Tz + t) * Hz + jf));
      u32 hp = (u32)f2bf(hn0) | ((u32)f2bf(hn1) << 16);
      __hip_atomic_store((u32*)Hwr + ((b_f * Hz + jf) >> 1), hp,
                         __ATOMIC_RELAXED, __HIP_MEMORY_SCOPE_AGENT);
      if (t == Tz - 1) {
        __builtin_nontemporal_store(hn0, final_h + b_f * Hz + jf);
        __builtin_nontemporal_store(hn1, final_h + b_f * Hz + jf + 1);
      }
      __hip_atomic_store((u64*)(accum + b_f * Hz + jf), (u64)0,
                         __ATOMIC_RELAXED, __HIP_MEMORY_SCOPE_AGENT);
      __syncthreads();
      if (tid == 0)
        __hip_atomic_store(&hflag[jc * 16], t + 1, __ATOMIC_RELEASE, __HIP_MEMORY_SCOPE_AGENT);
    }
  }
}

// ---------------- launcher ----------------

extern "C" void kernel_launch(void* const* d_in, const int* in_sizes, int n_in,
                              void* d_out, int out_size, void* d_ws, size_t ws_size,
                              hipStream_t stream) {
  const float* x   = (const float*)d_in[0];
  const int* lens  = (const int*)d_in[1];
  const float* Wi  = (const float*)d_in[2];
  const float* Wst = (const float*)d_in[3];
  const float* bst = (const float*)d_in[4];
  const float* Wp  = (const float*)d_in[5];

  float* outp    = (float*)d_out;
  float* final_h = outp + (size_t)Bz * Tz * Hz;
  float* final_c = final_h + (size_t)Bz * Hz;

  char* ws = (char*)d_ws;
  constexpr size_t OFF_H     = 0;                                   // 2x64 KB h bf16
  constexpr size_t OFF_ACC   = OFF_H + 2 * (size_t)Bz * Hz * 2;     // 131072
  constexpr size_t OFF_DONE  = OFF_ACC + (size_t)Bz * Hz * 4;       // 262144
  constexpr size_t OFF_AFLAG = OFF_DONE + 128;                      // 262272
  constexpr size_t OFF_HFLAG = OFF_AFLAG + 256 * 64;                // 278656
  constexpr size_t ZERO_END  = OFF_HFLAG + 32 * 64;                 // 280704
  constexpr size_t OFF_A     = 294912;                              // 2x512 KB abuf
  constexpr size_t OFF_WPK   = OFF_A + 2 * (size_t)Bz * Cz * 2;     // 32 MB wpk
  constexpr size_t OFF_WPP   = OFF_WPK + (size_t)16384 * 1024 * 2;  // 4 MB wpp
  constexpr size_t OFF_XB    = OFF_WPP + (size_t)Cz * Hz * 2;       // 32 MB xb
  constexpr size_t NEED      = OFF_XB + (size_t)Bz * Tz * Iz * 2;   // ~69.3 MB

  unsigned short* Hbuf = (unsigned short*)(ws + OFF_H);
  float* accum  = (float*)(ws + OFF_ACC);
  int* done     = (int*)(ws + OFF_DONE);
  int* aflag    = (int*)(ws + OFF_AFLAG);
  int* hflag    = (int*)(ws + OFF_HFLAG);
  unsigned short* abuf = (unsigned short*)(ws + OFF_A);
  short* wpk    = (short*)(ws + OFF_WPK);
  short* wpp    = (short*)(ws + OFF_WPP);
  unsigned short* xb = (unsigned short*)(ws + OFF_XB);

  const bool packed = (ws_size >= NEED);

  hipMemsetAsync(ws, 0, ZERO_END, stream);   // h0, accum, done, flags

  if (packed) {
    precast_wpk<<<8192, 256, 0, stream>>>(Wi, Wst, wpk);
    precast_wpp<<<1024, 256, 0, stream>>>(Wp, wpp);
    precast_x<<<16384, 256, 0, stream>>>(x, xb);
  }

  if (packed) {
    lstm_persist<true><<<NWG, 512, 0, stream>>>(x, xb, Wi, Wst, Wp, wpk, wpp, bst, lens,
                                                Hbuf, accum, done, aflag, hflag, abuf,
                                                outp, final_h, final_c);
  } else {
    lstm_persist<false><<<NWG, 512, 0, stream>>>(x, nullptr, Wi, Wst, Wp, nullptr, nullptr,
                                                 bst, lens, Hbuf, accum, done, aflag, hflag,
                                                 abuf, outp, final_h, final_c);
  }
}

// Round 7
// 8976.340 us; speedup vs baseline: 2.2738x; 2.2738x over previous
//
#include <hip/hip_runtime.h>
#include <cstdint>
#include <cstddef>

#define Bz 64
#define Tz 512
#define Iz 512
#define Hz 512
#define Cz 4096
#define NWG 256

typedef __attribute__((ext_vector_type(8))) short short8;
typedef __attribute__((ext_vector_type(4))) float floatx4;
typedef __attribute__((ext_vector_type(2))) float floatx2;
typedef unsigned long long u64;
typedef unsigned int u32;

union U16S8 { u64 u[2]; short8 s; };
union U8F2  { u64 u; float f[2]; };

__device__ __forceinline__ unsigned short f2bf(float f) {
  union { float f; unsigned u; } v; v.f = f;
  unsigned r = v.u + 0x7fffu + ((v.u >> 16) & 1u);
  return (unsigned short)(r >> 16);
}
__device__ __forceinline__ float bf2f(unsigned short h) {
  union { unsigned u; float f; } v; v.u = ((unsigned)h) << 16; return v.f;
}
__device__ __forceinline__ float sigmoidf_(float x) { return 1.0f / (1.0f + __expf(-x)); }

// 16-byte coherent read via two relaxed agent-scope u64 atomic loads (sc1: bypasses
// the non-coherent per-XCD L2 -> no acquire/invalidate needed anywhere).
__device__ __forceinline__ short8 ald16(const void* p) {
  u64* q = (u64*)p;
  U16S8 t;
  t.u[0] = __hip_atomic_load(q,     __ATOMIC_RELAXED, __HIP_MEMORY_SCOPE_AGENT);
  t.u[1] = __hip_atomic_load(q + 1, __ATOMIC_RELAXED, __HIP_MEMORY_SCOPE_AGENT);
  return t.s;
}

// ---------------- precast kernels (packed path) ----------------

__global__ __launch_bounds__(256) void precast_wpk(const float* __restrict__ Wi,
                                                   const float* __restrict__ Wst,
                                                   short* __restrict__ wpk) {
  int id = blockIdx.x * 256 + threadIdx.x;       // 0..2097151
  int l  = id & 63;
  int kt = (id >> 6) & 31;
  int nt = (id >> 11) & 3;
  int w  = id >> 13;
  int r  = nt * Cz + w * 16 + (l & 15);
  int k  = kt * 32 + (l >> 4) * 8;
  const float* p = (k < Iz) ? (Wi + (size_t)r * Iz + k)
                            : (Wst + (size_t)r * Hz + (k - Iz));
  short8 v;
  #pragma unroll
  for (int i = 0; i < 8; ++i) v[i] = (short)f2bf(p[i]);
  *(short8*)(wpk + (size_t)id * 8) = v;
}

__global__ __launch_bounds__(256) void precast_wpp(const float* __restrict__ Wp,
                                                   short* __restrict__ wpp) {
  int id = blockIdx.x * 256 + threadIdx.x;       // 0..262143
  int l  = id & 63;
  int kt = (id >> 6) & 15;
  int jc = (id >> 10) & 31;
  int kc = id >> 15;
  int j  = jc * 16 + (l & 15);
  int c  = kc * 512 + kt * 32 + (l >> 4) * 8;
  const float* p = Wp + (size_t)j * Cz + c;
  short8 v;
  #pragma unroll
  for (int i = 0; i < 8; ++i) v[i] = (short)f2bf(p[i]);
  *(short8*)(wpp + (size_t)id * 8) = v;
}

__global__ __launch_bounds__(256) void precast_x(const float* __restrict__ x,
                                                 unsigned short* __restrict__ xb) {
  size_t id = ((size_t)blockIdx.x * 256 + threadIdx.x) * 4;
  float4 v = *(const float4*)(x + id);
  ushort4 o;
  o.x = f2bf(v.x); o.y = f2bf(v.y); o.z = f2bf(v.z); o.w = f2bf(v.w);
  *(ushort4*)(xb + id) = o;
}

// ---------------- persistent kernel: 256 WGs x 512 thr ----------------
// WG w: gates for cells [w*16, w*16+16); proj tile kc=w>>5, jc=w&31.
// Coherence: h/abuf/accum/flags via relaxed sc1 atomics; read-only data cached.
// R3: R1's proven chunked pipeline (barrier-metered staging keeps L2 behavior sane;
// R2's one-shot staging doubled FETCH_SIZE and regressed 47%). New in R3: the
// CRITICAL-PATH weights live in LDS, loaded once before the t-loop:
//   - h-half gate weights (kt 16..31, 64 KB): post-hflag chunks read B via ds_read
//   - proj weights (16 KB): all proj chunks read B via ds_read
// x-half gate weights stay global (pre-hflag, overlapped, L2-hit in R1).
// Sync/flag structure byte-identical to passing R1. Length skipping retained.
template <bool PK>
__global__ __launch_bounds__(512, 2)
void lstm_persist(const float* __restrict__ xf, const unsigned short* __restrict__ xb,
                  const float* __restrict__ Wi, const float* __restrict__ Wst,
                  const float* __restrict__ Wp,
                  const short* __restrict__ wpk, const short* __restrict__ wpp,
                  const float* __restrict__ bstate, const int* __restrict__ lens,
                  unsigned short* __restrict__ Hbuf,   // 2 x [64][512] bf16
                  float* __restrict__ accum,           // [64][512] fp32, zeroed
                  int* __restrict__ done,              // [32], monotonic
                  int* __restrict__ aflag,             // [256] stride 16 ints
                  int* __restrict__ hflag,             // [32]  stride 16 ints
                  unsigned short* __restrict__ abuf,   // 2 x [64][4096] bf16
                  float* __restrict__ outp, float* __restrict__ final_h,
                  float* __restrict__ final_c) {
  __shared__ __align__(16) short astage[2][64 * 16 * 8];  // 2 x 16 KB
  __shared__ float glds[64 * 64];                         // 16 KB, XOR-swizzled cols
  __shared__ __align__(16) short wpk_h[4 * 16 * 64 * 8];  // 64 KB: [nt][kt-16][lane][8]
  __shared__ __align__(16) short wpp_l[16 * 64 * 8];      // 16 KB: [kt][lane][8]
  __shared__ int amLast;

  const int tid  = threadIdx.x;
  const int w    = blockIdx.x;
  const int lane = tid & 63;
  const int wv   = tid >> 6;        // 0..7
  const int lrow = lane & 15;
  const int lq   = lane >> 4;
  const int bt   = wv >> 1;         // gates batch 16-tile
  const int ntb  = (wv & 1) * 2;    // gates gate-pair base {0,2}
  const int jc   = w & 31;
  const int kc   = w >> 5;

  // block-head lengths (sorted decreasing => block max); uniform scalar loads
  const int l16_0 = lens[0];
  const int l16_1 = lens[16];
  const int l16_2 = lens[32];
  const int l16_3 = lens[48];

  // epilogue ownership: thread -> (batch b_e, cells cc2, cc2+1)
  const int b_e  = tid >> 3;        // 0..63
  const int cc2  = (tid & 7) * 2;   // 0..14
  const int cell2 = w * 16 + cc2;
  float bsv[4][2];
  #pragma unroll
  for (int g = 0; g < 4; ++g) {
    bsv[g][0] = bstate[g * Cz + cell2];
    bsv[g][1] = bstate[g * Cz + cell2 + 1];
  }
  const int len_e = lens[b_e];
  float c_reg[2] = {0.f, 0.f};

  // finalizer ownership: thread -> (batch b_f, cols j2, j2+1)
  const int b_f = tid >> 3;
  const int j2  = (tid & 7) * 2;
  const int jf  = jc * 16 + j2;
  const int len_f = lens[b_f];

  // ---- preload h-half gate weights (64 KB) + proj weights (16 KB) into LDS ----
  #pragma unroll
  for (int i = 0; i < 8; ++i) {
    int e   = i * 512 + tid;        // 0..4095 : [nt(4)][kth(16)][lane2(64)]
    int l2  = e & 63;
    int kth = (e >> 6) & 15;
    int nt  = e >> 10;
    short8 v;
    if (PK) {
      v = *(const short8*)(wpk + ((((size_t)w * 4 + nt) * 32 + (kth + 16)) * 64 + l2) * 8);
    } else {
      int r = nt * Cz + w * 16 + (l2 & 15);
      int k = (kth + 16) * 32 + (l2 >> 4) * 8;   // 512..1023 -> Wst only
      const float* p = Wst + (size_t)r * Hz + (k - Iz);
      #pragma unroll
      for (int x2 = 0; x2 < 8; ++x2) v[x2] = (short)f2bf(p[x2]);
    }
    *(short8*)(&wpk_h[e * 8]) = v;
  }
  #pragma unroll
  for (int i = 0; i < 2; ++i) {
    int e  = i * 512 + tid;         // 0..1023 : [kt(16)][lane(64)]
    int l2 = e & 63;
    int kt = e >> 6;
    short8 v;
    if (PK) {
      v = *(const short8*)(wpp + ((((size_t)kc * 32 + jc) * 16 + kt) * 64 + l2) * 8);
    } else {
      int j = jc * 16 + (l2 & 15);
      int c = kc * 512 + kt * 32 + (l2 >> 4) * 8;
      const float* p = Wp + (size_t)j * Cz + c;
      #pragma unroll
      for (int x2 = 0; x2 < 8; ++x2) v[x2] = (short)f2bf(p[x2]);
    }
    *(short8*)(&wpp_l[e * 8]) = v;
  }
  __syncthreads();

  for (int t = 0; t < Tz; ++t) {
    const unsigned short* Hread = Hbuf + (size_t)(t & 1) * Bz * Hz;
    unsigned short* abufT = abuf + (size_t)(t & 1) * Bz * Cz;

    // active 16-row blocks this step (monotone non-increasing in t)
    const int nb16   = (t < l16_0) + (t < l16_1) + (t < l16_2) + (t < l16_3);
    const int nbrows = nb16 << 4;

    // =================== gates phase ===================
    floatx4 acc0 = {0.f, 0.f, 0.f, 0.f};
    floatx4 acc1 = {0.f, 0.f, 0.f, 0.f};

    auto stage = [&](int q, int buf) {
      const int k0 = q * 128;
      #pragma unroll
      for (int u = 0; u < 2; ++u) {
        int idx = u * 512 + tid;    // 0..1023
        int row = idx >> 4;         // batch
        if (row >= nbrows) continue;   // dead block: skip load + LDS write
        int grp = idx & 15;
        int k = k0 + grp * 8;
        short8 val;
        if (k < Iz) {
          if (PK) {
            val = *(const short8*)(xb + ((size_t)row * Tz + t) * Iz + k);
          } else {
            const float* p = xf + ((size_t)row * Tz + t) * Iz + k;
            #pragma unroll
            for (int i = 0; i < 8; ++i) val[i] = (short)f2bf(p[i]);
          }
        } else {
          val = ald16(Hread + row * Hz + (k - Iz));   // coherent sc1 read
        }
        int phys = grp ^ (row & 15);
        *(short8*)(&astage[buf][(row * 16 + phys) * 8]) = val;
      }
    };

    stage(0, 0);            // chunk 0 is x-only: no h dependency
    __syncthreads();
    for (int q = 0; q < 8; ++q) {
      if (q == 3) {         // chunks 4..7 need h(t-1): wait here (x-half overlapped)
        if (tid < 32) {
          while (__hip_atomic_load(&hflag[tid * 16], __ATOMIC_RELAXED,
                                   __HIP_MEMORY_SCOPE_AGENT) < t)
            __builtin_amdgcn_s_sleep(1);
        }
        __syncthreads();
        __asm__ volatile("" ::: "memory");
      }
      if (q < 7) stage(q + 1, (q + 1) & 1);
      if (bt < nb16) {      // live batch tile only (wave-uniform branch)
        const short* sb = astage[q & 1];
        #pragma unroll
        for (int ktl = 0; ktl < 4; ++ktl) {
          const int kt = q * 4 + ktl;
          int grp  = ktl * 4 + lq;
          int phys = grp ^ lrow;
          short8 afr = *(const short8*)(sb + ((bt * 16 + lrow) * 16 + phys) * 8);
          short8 bfr0, bfr1;
          if (kt >= 16) {   // h-half weights: LDS-resident (critical path)
            const short* bp = &wpk_h[((ntb * 16 + (kt - 16)) * 64 + lane) * 8];
            bfr0 = *(const short8*)bp;
            bfr1 = *(const short8*)(bp + 16 * 64 * 8);
          } else if (PK) {
            const short* bp = wpk + ((((size_t)w * 4 + ntb) * 32 + kt) * 64 + lane) * 8;
            bfr0 = *(const short8*)bp;
            bfr1 = *(const short8*)(bp + (size_t)32 * 64 * 8);
          } else {
            #pragma unroll
            for (int hh = 0; hh < 2; ++hh) {
              int nt = ntb + hh;
              int r  = nt * Cz + w * 16 + lrow;
              int k  = kt * 32 + lq * 8;     // < 512 -> Wi only
              const float* p = Wi + (size_t)r * Iz + k;
              short8 v;
              #pragma unroll
              for (int i = 0; i < 8; ++i) v[i] = (short)f2bf(p[i]);
              if (hh == 0) bfr0 = v; else bfr1 = v;
            }
          }
          acc0 = __builtin_amdgcn_mfma_f32_16x16x32_bf16(afr, bfr0, acc0, 0, 0, 0);
          acc1 = __builtin_amdgcn_mfma_f32_16x16x32_bf16(afr, bfr1, acc1, 0, 0, 0);
        }
      }
      __syncthreads();
    }

    if (bt < nb16) {  // spill gate tile to LDS; col n = gate*16 + cell, phys col = n ^ row
      const int sb0 = bt * 16 + lq * 4;
      const int n0  = ntb * 16 + lrow;
      #pragma unroll
      for (int r = 0; r < 4; ++r) {
        int row = sb0 + r;
        glds[row * 64 + ((n0 ^ row) & 63)]        = acc0[r];
        glds[row * 64 + (((n0 + 16) ^ row) & 63)] = acc1[r];
      }
    }
    __syncthreads();
    {  // fp32 epilogue: 2 cells per thread, c in registers, packed sc1 store
      if (b_e < nbrows) {
        float a_out[2];
        #pragma unroll
        for (int e = 0; e < 2; ++e) {
          int cc = cc2 + e;
          float g0 = glds[b_e * 64 + (((0  + cc) ^ b_e) & 63)] + bsv[0][e];
          float g1 = glds[b_e * 64 + (((16 + cc) ^ b_e) & 63)] + bsv[1][e];
          float g2 = glds[b_e * 64 + (((32 + cc) ^ b_e) & 63)] + bsv[2][e];
          float g3 = glds[b_e * 64 + (((48 + cc) ^ b_e) & 63)] + bsv[3][e];
          float mem = sigmoidf_(g0) * tanhf(g2) + sigmoidf_(g1) * c_reg[e];
          mem = fminf(fmaxf(mem, -3.f), 3.f);
          bool active = t < len_e;
          c_reg[e] = active ? mem : c_reg[e];
          a_out[e] = sigmoidf_(g3) * tanhf(mem);
        }
        u32 pk2 = (u32)f2bf(a_out[0]) | ((u32)f2bf(a_out[1]) << 16);
        __hip_atomic_store((u32*)abufT + (((size_t)b_e * Cz + cell2) >> 1), pk2,
                           __ATOMIC_RELAXED, __HIP_MEMORY_SCOPE_AGENT);
      }
      if (t == Tz - 1) {
        __builtin_nontemporal_store(c_reg[0], final_c + (size_t)b_e * Cz + cell2);
        __builtin_nontemporal_store(c_reg[1], final_c + (size_t)b_e * Cz + cell2 + 1);
      }
    }
    __syncthreads();            // drain all waves' abuf stores
    if (tid == 0)               // publish (release: waitcnt + wbl2, no invalidate)
      __hip_atomic_store(&aflag[w * 16], t + 1, __ATOMIC_RELEASE, __HIP_MEMORY_SCOPE_AGENT);

    // ---- wait: the 32 producers of abuf columns [kc*512, kc*512+512) ----
    if (tid < 32) {
      while (__hip_atomic_load(&aflag[(kc * 32 + tid) * 16], __ATOMIC_RELAXED,
                               __HIP_MEMORY_SCOPE_AGENT) < t + 1)
        __builtin_amdgcn_s_sleep(1);
    }
    __syncthreads();
    __asm__ volatile("" ::: "memory");

    // =================== projection phase ===================
    floatx4 pacc = {0.f, 0.f, 0.f, 0.f};

    auto pstage = [&](int ch, int buf) {
      #pragma unroll
      for (int u = 0; u < 2; ++u) {
        int idx = u * 512 + tid;    // 0..1023
        int row = idx >> 4;
        if (row >= nbrows) continue;   // dead block: skip load + LDS write
        int grp = idx & 15;
        int k   = kc * 512 + ch * 128 + grp * 8;
        short8 v = ald16(abufT + (size_t)row * Cz + k);   // coherent sc1 read
        int phys = grp ^ (row & 15);
        *(short8*)(&astage[buf][(row * 16 + phys) * 8]) = v;
      }
    };

    pstage(0, 0);
    __syncthreads();
    for (int ch = 0; ch < 4; ++ch) {
      if (ch < 3) pstage(ch + 1, (ch + 1) & 1);
      if (wv < nb16) {  // live row-tiles only (waves 4..7 / dead tiles just stage)
        const short* sb = astage[ch & 1];
        #pragma unroll
        for (int ktl = 0; ktl < 4; ++ktl) {
          int kt   = ch * 4 + ktl;
          int grp  = ktl * 4 + lq;
          int phys = grp ^ lrow;
          short8 afr = *(const short8*)(sb + ((wv * 16 + lrow) * 16 + phys) * 8);
          short8 bfr = *(const short8*)(&wpp_l[(kt * 64 + lane) * 8]);  // LDS-resident
          pacc = __builtin_amdgcn_mfma_f32_16x16x32_bf16(afr, bfr, pacc, 0, 0, 0);
        }
      }
      __syncthreads();
    }
    if (wv < nb16) {
      const int jcol = jc * 16 + lrow;
      #pragma unroll
      for (int r = 0; r < 4; ++r)
        unsafeAtomicAdd(&accum[(wv * 16 + lq * 4 + r) * Hz + jcol], pacc[r]);
    }
    __syncthreads();            // drain atomic adds
    if (tid == 0) {
      int old = __hip_atomic_fetch_add(&done[jc], 1, __ATOMIC_RELEASE, __HIP_MEMORY_SCOPE_AGENT);
      amLast = (old == 8 * (t + 1) - 1) ? 1 : 0;
    }
    __syncthreads();
    if (amLast) {  // last of 8 kc-partials: finalize h + output, 2 cols/thread
      unsigned short* Hwr = Hbuf + (size_t)((t & 1) ^ 1) * Bz * Hz;
      U8F2 pa;
      pa.u = __hip_atomic_load((u64*)(accum + b_f * Hz + jf),
                               __ATOMIC_RELAXED, __HIP_MEMORY_SCOPE_AGENT);
      float v0 = fminf(fmaxf(pa.f[0], -3.f), 3.f);
      float v1 = fminf(fmaxf(pa.f[1], -3.f), 3.f);
      bool active = t < len_f;
      u32 ho = __hip_atomic_load((u32*)Hread + ((b_f * Hz + jf) >> 1),
                                 __ATOMIC_RELAXED, __HIP_MEMORY_SCOPE_AGENT);
      float hn0 = active ? v0 : bf2f((unsigned short)(ho & 0xffff));
      float hn1 = active ? v1 : bf2f((unsigned short)(ho >> 16));
      floatx2 ov = {active ? v0 : 0.f, active ? v1 : 0.f};
      __builtin_nontemporal_store(ov, (floatx2*)(outp + ((size_t)b_f * Tz + t) * Hz + jf));
      u32 hp = (u32)f2bf(hn0) | ((u32)f2bf(hn1) << 16);
      __hip_atomic_store((u32*)Hwr + ((b_f * Hz + jf) >> 1), hp,
                         __ATOMIC_RELAXED, __HIP_MEMORY_SCOPE_AGENT);
      if (t == Tz - 1) {
        __builtin_nontemporal_store(hn0, final_h + b_f * Hz + jf);
        __builtin_nontemporal_store(hn1, final_h + b_f * Hz + jf + 1);
      }
      __hip_atomic_store((u64*)(accum + b_f * Hz + jf), (u64)0,
                         __ATOMIC_RELAXED, __HIP_MEMORY_SCOPE_AGENT);
      __syncthreads();
      if (tid == 0)
        __hip_atomic_store(&hflag[jc * 16], t + 1, __ATOMIC_RELEASE, __HIP_MEMORY_SCOPE_AGENT);
    }
  }
}

// ---------------- launcher ----------------

extern "C" void kernel_launch(void* const* d_in, const int* in_sizes, int n_in,
                              void* d_out, int out_size, void* d_ws, size_t ws_size,
                              hipStream_t stream) {
  const float* x   = (const float*)d_in[0];
  const int* lens  = (const int*)d_in[1];
  const float* Wi  = (const float*)d_in[2];
  const float* Wst = (const float*)d_in[3];
  const float* bst = (const float*)d_in[4];
  const float* Wp  = (const float*)d_in[5];

  float* outp    = (float*)d_out;
  float* final_h = outp + (size_t)Bz * Tz * Hz;
  float* final_c = final_h + (size_t)Bz * Hz;

  char* ws = (char*)d_ws;
  constexpr size_t OFF_H     = 0;                                   // 2x64 KB h bf16
  constexpr size_t OFF_ACC   = OFF_H + 2 * (size_t)Bz * Hz * 2;     // 131072
  constexpr size_t OFF_DONE  = OFF_ACC + (size_t)Bz * Hz * 4;       // 262144
  constexpr size_t OFF_AFLAG = OFF_DONE + 128;                      // 262272
  constexpr size_t OFF_HFLAG = OFF_AFLAG + 256 * 64;                // 278656
  constexpr size_t ZERO_END  = OFF_HFLAG + 32 * 64;                 // 280704
  constexpr size_t OFF_A     = 294912;                              // 2x512 KB abuf
  constexpr size_t OFF_WPK   = OFF_A + 2 * (size_t)Bz * Cz * 2;     // 32 MB wpk
  constexpr size_t OFF_WPP   = OFF_WPK + (size_t)16384 * 1024 * 2;  // 4 MB wpp
  constexpr size_t OFF_XB    = OFF_WPP + (size_t)Cz * Hz * 2;       // 32 MB xb
  constexpr size_t NEED      = OFF_XB + (size_t)Bz * Tz * Iz * 2;   // ~69.3 MB

  unsigned short* Hbuf = (unsigned short*)(ws + OFF_H);
  float* accum  = (float*)(ws + OFF_ACC);
  int* done     = (int*)(ws + OFF_DONE);
  int* aflag    = (int*)(ws + OFF_AFLAG);
  int* hflag    = (int*)(ws + OFF_HFLAG);
  unsigned short* abuf = (unsigned short*)(ws + OFF_A);
  short* wpk    = (short*)(ws + OFF_WPK);
  short* wpp    = (short*)(ws + OFF_WPP);
  unsigned short* xb = (unsigned short*)(ws + OFF_XB);

  const bool packed = (ws_size >= NEED);

  hipMemsetAsync(ws, 0, ZERO_END, stream);   // h0, accum, done, flags

  if (packed) {
    precast_wpk<<<8192, 256, 0, stream>>>(Wi, Wst, wpk);
    precast_wpp<<<1024, 256, 0, stream>>>(Wp, wpp);
    precast_x<<<16384, 256, 0, stream>>>(x, xb);
  }

  if (packed) {
    lstm_persist<true><<<NWG, 512, 0, stream>>>(x, xb, Wi, Wst, Wp, wpk, wpp, bst, lens,
                                                Hbuf, accum, done, aflag, hflag, abuf,
                                                outp, final_h, final_c);
  } else {
    lstm_persist<false><<<NWG, 512, 0, stream>>>(x, nullptr, Wi, Wst, Wp, nullptr, nullptr,
                                                 bst, lens, Hbuf, accum, done, aflag, hflag,
                                                 abuf, outp, final_h, final_c);
  }
}